// Round 11
// baseline (2846.419 us; speedup 1.0000x reference)
//
#include <hip/hip_runtime.h>
#include <hip/hip_bf16.h>

typedef __attribute__((ext_vector_type(8))) __bf16 bf16x8;
typedef __attribute__((ext_vector_type(4))) float f32x4;

__device__ __forceinline__ void gload_lds16(const void* g, void* lds) {
    __builtin_amdgcn_global_load_lds(
        (const __attribute__((address_space(1))) void*)g,
        (__attribute__((address_space(3))) void*)lds, 16, 0, 0);
}

// ---------------------------------------------------------------------------
// int5 block-64 MSE quant-dequant -> bf16, both weights in one launch
// ---------------------------------------------------------------------------
__global__ __launch_bounds__(256) void quant2_bf16_kernel(
    const float* __restrict__ w0, __hip_bfloat16* __restrict__ o0,
    const float* __restrict__ w1, __hip_bfloat16* __restrict__ o1, int nEach)
{
#pragma clang fp contract(off)
    int b = blockIdx.x * 256 + threadIdx.x;
    const float* w; __hip_bfloat16* o; int bb;
    if (b < nEach) { w = w0; o = o0; bb = b; }
    else           { w = w1; o = o1; bb = b - nEach; }
    const float4* src = (const float4*)(w + (size_t)bb * 64);
    float v[64];
#pragma unroll
    for (int i = 0; i < 16; ++i) {
        float4 t = src[i];
        v[i*4+0] = t.x; v[i*4+1] = t.y; v[i*4+2] = t.z; v[i*4+3] = t.w;
    }
    float amax = 0.0f;
#pragma unroll
    for (int i = 0; i < 64; ++i) amax = fmaxf(amax, fabsf(v[i]));
    float base = fmaxf(amax, 1e-8f) / 15.0f;

    float best_err = __builtin_inff();
    float best_scale = base, best_rs = 0.0f;
    for (int k = 0; k < 16; ++k) {
        double sd = (k == 15) ? 1.0 : ((double)k * (0.6 / 15.0) + 0.4);
        float scale = base * (float)sd;
        float rs = 1.0f / scale;
        float err = 0.0f;
#pragma unroll
        for (int i = 0; i < 64; ++i) {
            float q = rintf(v[i] * rs);
            q = fminf(fmaxf(q, -15.0f), 15.0f);
            float d = q * scale - v[i];
            err = err + d * d;
        }
        if (err < best_err) { best_err = err; best_scale = scale; best_rs = rs; }
    }
    __hip_bfloat16* dst = o + (size_t)bb * 64;
#pragma unroll
    for (int i = 0; i < 64; ++i) {
        float q = rintf(v[i] * best_rs);
        q = fminf(fmaxf(q, -15.0f), 15.0f);
        dst[i] = __float2bfloat16(q * best_scale);
    }
}

__global__ __launch_bounds__(256) void f32_to_bf16_kernel(
    const float* __restrict__ in, __hip_bfloat16* __restrict__ out, int n8)
{
    int i = blockIdx.x * 256 + threadIdx.x;
    if (i >= n8) return;
    const float4* p = (const float4*)(in + (size_t)i * 8);
    float4 a = p[0], b = p[1];
    alignas(16) __hip_bfloat16 r[8];
    r[0] = __float2bfloat16(a.x); r[1] = __float2bfloat16(a.y);
    r[2] = __float2bfloat16(a.z); r[3] = __float2bfloat16(a.w);
    r[4] = __float2bfloat16(b.x); r[5] = __float2bfloat16(b.y);
    r[6] = __float2bfloat16(b.z); r[7] = __float2bfloat16(b.w);
    *(uint4*)(out + (size_t)i * 8) = *(const uint4*)r;
}

// ---------------------------------------------------------------------------
// 256x256 tile, BK=64, 8 waves (2Mx4N), 16x16x32 MFMA, swizzled LDS
// (phys = logical ^ ((row&7)<<4)), linear wave-contiguous staging.
// SB=0 (dbuf, 128KB, 1 block/CU): r6 schedule -- stage t+1 at tile start,
//   compute, vmcnt(0), barrier.
// SB=1 (single buffer, 64KB, __launch_bounds__(512,4) -> 2 blocks/CU):
//   compute tile t -> barrier(all reads done) -> stage t+1 -> vmcnt(0) ->
//   barrier. Exposed staging drain is covered by the co-resident block's
//   compute phase (cross-block TLP); 16 waves from 2 independent barrier
//   domains keep matrix+LDS pipes concurrently fed.
// Ledger(SB=1): RAW -- stage of tile t drained by vmcnt(0)+barrier before
// tile t's reads. WAR -- stage of t+1 issued only after the barrier that
// all waves reach having consumed every ds_read of tile t (MFMA operands
// force lgkm waits before consumption).
// ---------------------------------------------------------------------------
#define LDA2(d, base, s) { \
    d[0] = *(const bf16x8*)(smem + (base) + aB + (s)*2048u + cb0); \
    d[1] = *(const bf16x8*)(smem + (base) + aB + (s)*2048u + cb1); }

#define LDB8(base) { \
    bf[0][0] = *(const bf16x8*)(smem + (base) + bB + 0u    + cb0); \
    bf[0][1] = *(const bf16x8*)(smem + (base) + bB + 0u    + cb1); \
    bf[1][0] = *(const bf16x8*)(smem + (base) + bB + 2048u + cb0); \
    bf[1][1] = *(const bf16x8*)(smem + (base) + bB + 2048u + cb1); \
    bf[2][0] = *(const bf16x8*)(smem + (base) + bB + 4096u + cb0); \
    bf[2][1] = *(const bf16x8*)(smem + (base) + bB + 4096u + cb1); \
    bf[3][0] = *(const bf16x8*)(smem + (base) + bB + 6144u + cb0); \
    bf[3][1] = *(const bf16x8*)(smem + (base) + bB + 6144u + cb1); }

#define MF8(q, a2) { \
    acc[q][0] = __builtin_amdgcn_mfma_f32_16x16x32_bf16(a2[0], bf[0][0], acc[q][0],0,0,0); \
    acc[q][0] = __builtin_amdgcn_mfma_f32_16x16x32_bf16(a2[1], bf[0][1], acc[q][0],0,0,0); \
    acc[q][1] = __builtin_amdgcn_mfma_f32_16x16x32_bf16(a2[0], bf[1][0], acc[q][1],0,0,0); \
    acc[q][1] = __builtin_amdgcn_mfma_f32_16x16x32_bf16(a2[1], bf[1][1], acc[q][1],0,0,0); \
    acc[q][2] = __builtin_amdgcn_mfma_f32_16x16x32_bf16(a2[0], bf[2][0], acc[q][2],0,0,0); \
    acc[q][2] = __builtin_amdgcn_mfma_f32_16x16x32_bf16(a2[1], bf[2][1], acc[q][2],0,0,0); \
    acc[q][3] = __builtin_amdgcn_mfma_f32_16x16x32_bf16(a2[0], bf[3][0], acc[q][3],0,0,0); \
    acc[q][3] = __builtin_amdgcn_mfma_f32_16x16x32_bf16(a2[1], bf[3][1], acc[q][3],0,0,0); }

#define STAGE(base, eoff, ldsOff) \
    gload_lds16((base) + (size_t)((eoff) + voff), smem + (ldsOff) + wOff)

#define STAGE8(dstOff, kk) { \
    STAGE(uA, (kk),          (dstOff) + 0u); \
    STAGE(uA, (kk) + K64,    (dstOff) + 8192u); \
    STAGE(uA, (kk) + 2u*K64, (dstOff) + 16384u); \
    STAGE(uA, (kk) + 3u*K64, (dstOff) + 24576u); \
    STAGE(uB, (kk),          (dstOff) + 32768u); \
    STAGE(uB, (kk) + K64,    (dstOff) + 40960u); \
    STAGE(uB, (kk) + 2u*K64, (dstOff) + 49152u); \
    STAGE(uB, (kk) + 3u*K64, (dstOff) + 57344u); }

#define COMPUTE_BODY(bufOff) { \
    LDB8(bufOff); \
    LDA2(aC0, (bufOff), 0u); LDA2(aC1, (bufOff), 1u); \
    __builtin_amdgcn_s_setprio(1); \
    MF8(0, aC0); LDA2(aC0, (bufOff), 2u); \
    MF8(1, aC1); LDA2(aC1, (bufOff), 3u); \
    MF8(2, aC0); LDA2(aC0, (bufOff), 4u); \
    MF8(3, aC1); LDA2(aC1, (bufOff), 5u); \
    MF8(4, aC0); LDA2(aC0, (bufOff), 6u); \
    MF8(5, aC1); LDA2(aC1, (bufOff), 7u); \
    MF8(6, aC0); MF8(7, aC1); \
    __builtin_amdgcn_s_setprio(0); }

#define SB0() __builtin_amdgcn_sched_barrier(0)
#define BARRIER() { SB0(); __builtin_amdgcn_s_barrier(); SB0(); }

template <int EPI, int SB>
__global__ __launch_bounds__(512, SB ? 4 : 1) void gemm256_kernel(
    const __hip_bfloat16* __restrict__ A,   // M x K
    const __hip_bfloat16* __restrict__ B,   // N x K
    void* __restrict__ Cout, int M, int N, int K)
{
    extern __shared__ char smem[];

    const int t    = threadIdx.x;
    const int lane = t & 63;
    const int w    = t >> 6;
    const int wr   = w >> 2;
    const int wc   = w & 3;
    const int lo   = lane & 15;
    const int hi   = lane >> 4;
    const uint wOff = (uint)w * 1024u;

    const int cpx = gridDim.x >> 3;
    int bid = blockIdx.x;
    bid = (bid & 7) * cpx + (bid >> 3);
    const int nN = N >> 8;
    const int bm = bid / nN;
    const int bn = bid % nN;
    const int rowBase = bm << 8;
    const int colBase = bn << 8;

    const __hip_bfloat16* uA = A + (size_t)rowBase * (size_t)K;
    const __hip_bfloat16* uB = B + (size_t)colBase * (size_t)K;
    uint o0 = (uint)t * 16u;
    uint p0 = o0 ^ (((o0 >> 7) & 7u) << 4);
    const uint voff = (p0 >> 7) * (uint)K + ((p0 & 127u) >> 1);
    const uint K64 = (uint)K * 64u;

    const uint sw  = (uint)(lo & 7) << 4;
    const uint aB  = (uint)wr * 16384u + (uint)lo * 128u;
    const uint bB  = 32768u + (uint)(wc >> 1) * 16384u
                   + ((uint)(wc & 1) * 64u + (uint)lo) * 128u;
    const uint cb0 = ((uint)hi * 16u) ^ sw;
    const uint cb1 = (64u + (uint)hi * 16u) ^ sw;

    f32x4 acc[8][4] = {};
    bf16x8 aC0[2], aC1[2], bf[4][2];

    // ---- prologue: tile0 -> buf0 ----
    STAGE8(0u, 0u);
    asm volatile("s_waitcnt vmcnt(0)" ::: "memory");
    BARRIER();

    const int NT = K >> 6;
    if (SB) {
        // single buffer, 2 blocks/CU: compute -> barrier -> stage -> barrier
        for (int tt = 0; tt < NT; ++tt) {
            const bool pf = (tt + 1 < NT);
            const uint kN = ((uint)(tt + 1)) << 6;
            COMPUTE_BODY(0u);
            if (pf) {
                BARRIER();                   // all waves consumed tile tt
                STAGE8(0u, kN);
                asm volatile("s_waitcnt vmcnt(0)" ::: "memory");
                BARRIER();                   // tile tt+1 ready
            }
        }
    } else {
        // double buffer, 1 block/CU (r6 schedule)
        for (int tt = 0; tt < NT; ++tt) {
            const uint bufOff = (uint)(tt & 1) * 65536u;
            const uint nxtOff = bufOff ^ 65536u;
            const bool pf = (tt + 1 < NT);
            const uint kN = ((uint)(tt + 1)) << 6;
            if (pf) STAGE8(nxtOff, kN);
            SB0();
            COMPUTE_BODY(bufOff);
            if (pf) asm volatile("s_waitcnt vmcnt(0)" ::: "memory");
            BARRIER();
        }
    }

    // ---- epilogue: C/D layout col=lane&15, row=(lane>>4)*4+r ----
    if (EPI == 0) {
        __hip_bfloat16* Cb = (__hip_bfloat16*)Cout;
#pragma unroll
        for (int i = 0; i < 8; ++i)
#pragma unroll
            for (int j = 0; j < 4; ++j)
#pragma unroll
                for (int r = 0; r < 4; ++r) {
                    size_t row = rowBase + wr*128 + i*16 + hi*4 + r;
                    size_t col = colBase + wc*64 + j*16 + lo;
                    float v = fmaxf(acc[i][j][r], 0.0f);
                    Cb[row * N + col] = __float2bfloat16(v * v);
                }
    } else {
        float* Cf = (float*)Cout;
#pragma unroll
        for (int i = 0; i < 8; ++i)
#pragma unroll
            for (int j = 0; j < 4; ++j)
#pragma unroll
                for (int r = 0; r < 4; ++r) {
                    size_t row = rowBase + wr*128 + i*16 + hi*4 + r;
                    size_t col = colBase + wc*64 + j*16 + lo;
                    Cf[row * N + col] = acc[i][j][r];
                }
    }
}

// ---------------------------------------------------------------------------
extern "C" void kernel_launch(void* const* d_in, const int* in_sizes, int n_in,
                              void* d_out, int out_size, void* d_ws, size_t ws_size,
                              hipStream_t stream) {
    const float* x      = (const float*)d_in[0];  // 8192 x 2048
    const float* w_fc   = (const float*)d_in[1];  // 8192 x 2048
    const float* w_proj = (const float*)d_in[2];  // 2048 x 8192
    float* out = (float*)d_out;                   // 8192 x 2048

    const int DIM = 2048, HID = 8192, M = 8192;

    char* ws = (char*)d_ws;
    __hip_bfloat16* Xb  = (__hip_bfloat16*)ws;
    __hip_bfloat16* Wfc = (__hip_bfloat16*)(ws + (size_t)M * DIM * 2);
    __hip_bfloat16* Wpj = (__hip_bfloat16*)(ws + (size_t)(M * DIM + (size_t)HID * DIM) * 2);
    __hip_bfloat16* H2  = (__hip_bfloat16*)(ws + (size_t)(M * DIM + 2 * (size_t)HID * DIM) * 2);

    (void)hipFuncSetAttribute((const void*)gemm256_kernel<0, 1>,
                              hipFuncAttributeMaxDynamicSharedMemorySize, 65536);
    (void)hipFuncSetAttribute((const void*)gemm256_kernel<1, 0>,
                              hipFuncAttributeMaxDynamicSharedMemorySize, 131072);

    int nblk = HID * DIM / 64;   // 262144 per weight
    quant2_bf16_kernel<<<2 * nblk / 256, 256, 0, stream>>>(
        w_fc, Wfc, w_proj, Wpj, nblk);

    int n8 = M * DIM / 8;
    f32_to_bf16_kernel<<<n8 / 256, 256, 0, stream>>>(x, Xb, n8);

    // H2 = bf16( relu(X @ Wfc^T)^2 )  [8192 x 8192]  -- SB=1, 2 blocks/CU
    gemm256_kernel<0, 1><<<(M/256)*(HID/256), 512, 65536, stream>>>(
        Xb, Wfc, (void*)H2, M, HID, DIM);

    // out = H2 @ Wpj^T  [8192 x 2048] f32  -- SB=0 (dbuf)
    gemm256_kernel<1, 0><<<(M/256)*(DIM/256), 512, 131072, stream>>>(
        H2, Wpj, (void*)out, M, DIM, HID);
}

// Round 12
// 683.928 us; speedup vs baseline: 4.1619x; 4.1619x over previous
//
#include <hip/hip_runtime.h>
#include <hip/hip_bf16.h>

typedef __attribute__((ext_vector_type(8))) __bf16 bf16x8;
typedef __attribute__((ext_vector_type(16))) float f32x16;

__device__ __forceinline__ void gload_lds16(const void* g, void* lds) {
    __builtin_amdgcn_global_load_lds(
        (const __attribute__((address_space(1))) void*)g,
        (__attribute__((address_space(3))) void*)lds, 16, 0, 0);
}

// ---------------------------------------------------------------------------
// int5 block-64 MSE quant-dequant -> bf16, both weights in one launch
// ---------------------------------------------------------------------------
__global__ __launch_bounds__(256) void quant2_bf16_kernel(
    const float* __restrict__ w0, __hip_bfloat16* __restrict__ o0,
    const float* __restrict__ w1, __hip_bfloat16* __restrict__ o1, int nEach)
{
#pragma clang fp contract(off)
    int b = blockIdx.x * 256 + threadIdx.x;
    const float* w; __hip_bfloat16* o; int bb;
    if (b < nEach) { w = w0; o = o0; bb = b; }
    else           { w = w1; o = o1; bb = b - nEach; }
    const float4* src = (const float4*)(w + (size_t)bb * 64);
    float v[64];
#pragma unroll
    for (int i = 0; i < 16; ++i) {
        float4 t = src[i];
        v[i*4+0] = t.x; v[i*4+1] = t.y; v[i*4+2] = t.z; v[i*4+3] = t.w;
    }
    float amax = 0.0f;
#pragma unroll
    for (int i = 0; i < 64; ++i) amax = fmaxf(amax, fabsf(v[i]));
    float base = fmaxf(amax, 1e-8f) / 15.0f;

    float best_err = __builtin_inff();
    float best_scale = base, best_rs = 0.0f;
    for (int k = 0; k < 16; ++k) {
        double sd = (k == 15) ? 1.0 : ((double)k * (0.6 / 15.0) + 0.4);
        float scale = base * (float)sd;
        float rs = 1.0f / scale;
        float err = 0.0f;
#pragma unroll
        for (int i = 0; i < 64; ++i) {
            float q = rintf(v[i] * rs);
            q = fminf(fmaxf(q, -15.0f), 15.0f);
            float d = q * scale - v[i];
            err = err + d * d;
        }
        if (err < best_err) { best_err = err; best_scale = scale; best_rs = rs; }
    }
    __hip_bfloat16* dst = o + (size_t)bb * 64;
#pragma unroll
    for (int i = 0; i < 64; ++i) {
        float q = rintf(v[i] * best_rs);
        q = fminf(fmaxf(q, -15.0f), 15.0f);
        dst[i] = __float2bfloat16(q * best_scale);
    }
}

__global__ __launch_bounds__(256) void f32_to_bf16_kernel(
    const float* __restrict__ in, __hip_bfloat16* __restrict__ out, int n8)
{
    int i = blockIdx.x * 256 + threadIdx.x;
    if (i >= n8) return;
    const float4* p = (const float4*)(in + (size_t)i * 8);
    float4 a = p[0], b = p[1];
    alignas(16) __hip_bfloat16 r[8];
    r[0] = __float2bfloat16(a.x); r[1] = __float2bfloat16(a.y);
    r[2] = __float2bfloat16(a.z); r[3] = __float2bfloat16(a.w);
    r[4] = __float2bfloat16(b.x); r[5] = __float2bfloat16(b.y);
    r[6] = __float2bfloat16(b.z); r[7] = __float2bfloat16(b.w);
    *(uint4*)(out + (size_t)i * 8) = *(const uint4*)r;
}

// ---------------------------------------------------------------------------
// 256x256 tile, BK=64, 4 waves (2Mx2N, wave = 128x128), MFMA 32x32x16.
// LDS identical to r6: row-major 64-row regions, phys = logical^((row&7)<<4),
// dbuf 2x64KB, linear wave-contiguous gload_lds staging (inverse-swz source).
// Per-wave reuse doubled vs 8-wave config -> LDS reads/tile 192KB -> 128KB.
// acc[4][4] f32x16 = 256 VGPR -> 1 wave/SIMD; frags ping-pong E/O sets.
// Frag (verified r7): A lane=row l5(+32m+128wr), k = s*16 + h2*8 + i.
//   byte addr = wr*16384 + m*4096 + l5*128 + ((s*32+h2*16) ^ ((l5&7)<<4))
//   (conflict-free: rows 0-7 granules (2s)^r cover all 8 -> all 32 banks)
// Schedule per K-tile (r6 skeleton): stage t+1 (16 gloads) -> RDS(s0,s1) ->
// MF16(s0) -> RDS(s2) -> MF16(s1) -> RDS(s3) -> MF16(s2) -> MF16(s3) ->
// vmcnt(0) -> barrier.  Ledger: RAW -- buf[cur] staged during t-1, drained
// by every wave's vmcnt(0) before the barrier ending t-1. WAR -- stagings
// into buf[nxt] overwrite data whose readers finished before that barrier.
// ---------------------------------------------------------------------------
#define SB0() __builtin_amdgcn_sched_barrier(0)
#define BARRIER() { SB0(); __builtin_amdgcn_s_barrier(); SB0(); }

#define RDS(aS, bS, bufOff, s) { \
    aS[0] = *(const bf16x8*)(smem + (bufOff) + aBase + 0u     + koff##s); \
    aS[1] = *(const bf16x8*)(smem + (bufOff) + aBase + 4096u  + koff##s); \
    aS[2] = *(const bf16x8*)(smem + (bufOff) + aBase + 8192u  + koff##s); \
    aS[3] = *(const bf16x8*)(smem + (bufOff) + aBase + 12288u + koff##s); \
    bS[0] = *(const bf16x8*)(smem + (bufOff) + bBase + 0u     + koff##s); \
    bS[1] = *(const bf16x8*)(smem + (bufOff) + bBase + 4096u  + koff##s); \
    bS[2] = *(const bf16x8*)(smem + (bufOff) + bBase + 8192u  + koff##s); \
    bS[3] = *(const bf16x8*)(smem + (bufOff) + bBase + 12288u + koff##s); }

#define MF16(aS, bS) { \
    _Pragma("unroll") \
    for (int m_ = 0; m_ < 4; ++m_) \
    _Pragma("unroll") \
      for (int n_ = 0; n_ < 4; ++n_) \
        acc[m_][n_] = __builtin_amdgcn_mfma_f32_32x32x16_bf16( \
            aS[m_], bS[n_], acc[m_][n_], 0, 0, 0); }

#define STAGE16(dstOff, kk) { \
    gload_lds16(uA + (size_t)(voff + 0u*K64 +       (kk)), smem + (dstOff) + 0u*8192u +         wOff); \
    gload_lds16(uA + (size_t)(voff + 0u*K64 + K32 + (kk)), smem + (dstOff) + 0u*8192u + 4096u + wOff); \
    gload_lds16(uA + (size_t)(voff + 1u*K64 +       (kk)), smem + (dstOff) + 1u*8192u +         wOff); \
    gload_lds16(uA + (size_t)(voff + 1u*K64 + K32 + (kk)), smem + (dstOff) + 1u*8192u + 4096u + wOff); \
    gload_lds16(uA + (size_t)(voff + 2u*K64 +       (kk)), smem + (dstOff) + 2u*8192u +         wOff); \
    gload_lds16(uA + (size_t)(voff + 2u*K64 + K32 + (kk)), smem + (dstOff) + 2u*8192u + 4096u + wOff); \
    gload_lds16(uA + (size_t)(voff + 3u*K64 +       (kk)), smem + (dstOff) + 3u*8192u +         wOff); \
    gload_lds16(uA + (size_t)(voff + 3u*K64 + K32 + (kk)), smem + (dstOff) + 3u*8192u + 4096u + wOff); \
    gload_lds16(uB + (size_t)(voff + 0u*K64 +       (kk)), smem + (dstOff) + 32768u + 0u*8192u +         wOff); \
    gload_lds16(uB + (size_t)(voff + 0u*K64 + K32 + (kk)), smem + (dstOff) + 32768u + 0u*8192u + 4096u + wOff); \
    gload_lds16(uB + (size_t)(voff + 1u*K64 +       (kk)), smem + (dstOff) + 32768u + 1u*8192u +         wOff); \
    gload_lds16(uB + (size_t)(voff + 1u*K64 + K32 + (kk)), smem + (dstOff) + 32768u + 1u*8192u + 4096u + wOff); \
    gload_lds16(uB + (size_t)(voff + 2u*K64 +       (kk)), smem + (dstOff) + 32768u + 2u*8192u +         wOff); \
    gload_lds16(uB + (size_t)(voff + 2u*K64 + K32 + (kk)), smem + (dstOff) + 32768u + 2u*8192u + 4096u + wOff); \
    gload_lds16(uB + (size_t)(voff + 3u*K64 +       (kk)), smem + (dstOff) + 32768u + 3u*8192u +         wOff); \
    gload_lds16(uB + (size_t)(voff + 3u*K64 + K32 + (kk)), smem + (dstOff) + 32768u + 3u*8192u + 4096u + wOff); }

template <int EPI>  // 0: C=bf16(relu(acc)^2), 1: C=f32 acc
__global__ __launch_bounds__(256, 1) void gemm256_kernel(
    const __hip_bfloat16* __restrict__ A,   // M x K
    const __hip_bfloat16* __restrict__ B,   // N x K
    void* __restrict__ Cout, int M, int N, int K)
{
    extern __shared__ char smem[];

    const int t    = threadIdx.x;
    const int lane = t & 63;
    const int w    = t >> 6;        // 0..3
    const int wr   = w >> 1;        // 0..1 (128-row half)
    const int wc   = w & 1;         // 0..1 (128-col half)
    const int l5   = lane & 31;
    const int h2   = lane >> 5;
    const uint wOff = (uint)w * 1024u;

    // XCD-aware swizzle (grids are multiples of 8)
    const int cpx = gridDim.x >> 3;
    int bid = blockIdx.x;
    bid = (bid & 7) * cpx + (bid >> 3);
    const int nN = N >> 8;
    const int bm = bid / nN;
    const int bn = bid % nN;
    const int rowBase = bm << 8;
    const int colBase = bn << 8;

    const __hip_bfloat16* uA = A + (size_t)rowBase * (size_t)K;
    const __hip_bfloat16* uB = B + (size_t)colBase * (size_t)K;

    // staging source (inverse-swizzled, linear LDS dest); t=0..255 -> rows 0..31
    uint o0 = (uint)t * 16u;
    uint p0 = o0 ^ (((o0 >> 7) & 7u) << 4);
    const uint voff = (p0 >> 7) * (uint)K + ((p0 & 127u) >> 1);
    const uint K64 = (uint)K * 64u;
    const uint K32 = (uint)K * 32u;

    // fragment read addressing
    const uint sw2   = ((uint)(l5 & 7)) << 4;
    const uint aBase = (uint)wr * 16384u + (uint)l5 * 128u;
    const uint bBase = 32768u + (uint)wc * 16384u + (uint)l5 * 128u;
    const uint koff0 = ((uint)h2 * 16u)        ^ sw2;
    const uint koff1 = (32u  + (uint)h2 * 16u) ^ sw2;
    const uint koff2 = (64u  + (uint)h2 * 16u) ^ sw2;
    const uint koff3 = (96u  + (uint)h2 * 16u) ^ sw2;

    f32x16 acc[4][4] = {};
    bf16x8 aE[4], bE[4], aO[4], bO[4];

    // ---- prologue: tile0 -> buf0 ----
    STAGE16(0u, 0u);
    asm volatile("s_waitcnt vmcnt(0)" ::: "memory");
    BARRIER();

    const int NT = K >> 6;
    for (int tt = 0; tt < NT; ++tt) {
        const uint bufOff = (uint)(tt & 1) * 65536u;
        const uint nxtOff = bufOff ^ 65536u;
        const bool pf = (tt + 1 < NT);
        const uint kN = ((uint)(tt + 1)) << 6;

        if (pf) STAGE16(nxtOff, kN);
        SB0();   // pin stagings at tile start

        RDS(aE, bE, bufOff, 0);
        RDS(aO, bO, bufOff, 1);

        __builtin_amdgcn_s_setprio(1); MF16(aE, bE); __builtin_amdgcn_s_setprio(0);
        RDS(aE, bE, bufOff, 2);
        __builtin_amdgcn_s_setprio(1); MF16(aO, bO); __builtin_amdgcn_s_setprio(0);
        RDS(aO, bO, bufOff, 3);
        __builtin_amdgcn_s_setprio(1); MF16(aE, bE); __builtin_amdgcn_s_setprio(0);
        __builtin_amdgcn_s_setprio(1); MF16(aO, bO); __builtin_amdgcn_s_setprio(0);

        if (pf) asm volatile("s_waitcnt vmcnt(0)" ::: "memory");
        BARRIER();
    }

    // ---- epilogue: 32x32 C/D layout col=lane&31, row=(r&3)+8*(r>>2)+4*h2 ----
    if (EPI == 0) {
        __hip_bfloat16* Cb = (__hip_bfloat16*)Cout;
#pragma unroll
        for (int m = 0; m < 4; ++m)
#pragma unroll
            for (int n = 0; n < 4; ++n)
#pragma unroll
                for (int r = 0; r < 16; ++r) {
                    size_t row = rowBase + wr*128 + m*32 + (r & 3) + 8*(r >> 2) + 4*h2;
                    size_t col = colBase + wc*128 + n*32 + l5;
                    float v = fmaxf(acc[m][n][r], 0.0f);
                    Cb[row * N + col] = __float2bfloat16(v * v);
                }
    } else {
        float* Cf = (float*)Cout;
#pragma unroll
        for (int m = 0; m < 4; ++m)
#pragma unroll
            for (int n = 0; n < 4; ++n)
#pragma unroll
                for (int r = 0; r < 16; ++r) {
                    size_t row = rowBase + wr*128 + m*32 + (r & 3) + 8*(r >> 2) + 4*h2;
                    size_t col = colBase + wc*128 + n*32 + l5;
                    Cf[row * N + col] = acc[m][n][r];
                }
    }
}

// ---------------------------------------------------------------------------
extern "C" void kernel_launch(void* const* d_in, const int* in_sizes, int n_in,
                              void* d_out, int out_size, void* d_ws, size_t ws_size,
                              hipStream_t stream) {
    const float* x      = (const float*)d_in[0];  // 8192 x 2048
    const float* w_fc   = (const float*)d_in[1];  // 8192 x 2048
    const float* w_proj = (const float*)d_in[2];  // 2048 x 8192
    float* out = (float*)d_out;                   // 8192 x 2048

    const int DIM = 2048, HID = 8192, M = 8192;

    char* ws = (char*)d_ws;
    __hip_bfloat16* Xb  = (__hip_bfloat16*)ws;
    __hip_bfloat16* Wfc = (__hip_bfloat16*)(ws + (size_t)M * DIM * 2);
    __hip_bfloat16* Wpj = (__hip_bfloat16*)(ws + (size_t)(M * DIM + (size_t)HID * DIM) * 2);
    __hip_bfloat16* H2  = (__hip_bfloat16*)(ws + (size_t)(M * DIM + 2 * (size_t)HID * DIM) * 2);

    (void)hipFuncSetAttribute((const void*)gemm256_kernel<0>,
                              hipFuncAttributeMaxDynamicSharedMemorySize, 131072);
    (void)hipFuncSetAttribute((const void*)gemm256_kernel<1>,
                              hipFuncAttributeMaxDynamicSharedMemorySize, 131072);

    int nblk = HID * DIM / 64;   // 262144 per weight
    quant2_bf16_kernel<<<2 * nblk / 256, 256, 0, stream>>>(
        w_fc, Wfc, w_proj, Wpj, nblk);

    int n8 = M * DIM / 8;
    f32_to_bf16_kernel<<<n8 / 256, 256, 0, stream>>>(x, Xb, n8);

    // H2 = bf16( relu(X @ Wfc^T)^2 )  [8192 x 8192]
    gemm256_kernel<0><<<(M/256)*(HID/256), 256, 131072, stream>>>(
        Xb, Wfc, (void*)H2, M, HID, DIM);

    // out = H2 @ Wpj^T  [8192 x 2048] f32
    gemm256_kernel<1><<<(M/256)*(DIM/256), 256, 131072, stream>>>(
        H2, Wpj, (void*)out, M, DIM, HID);
}

// Round 13
// 628.462 us; speedup vs baseline: 4.5292x; 1.0883x over previous
//
#include <hip/hip_runtime.h>
#include <hip/hip_bf16.h>

typedef __attribute__((ext_vector_type(8))) __bf16 bf16x8;
typedef __attribute__((ext_vector_type(4))) float f32x4;

__device__ __forceinline__ void gload_lds16(const void* g, void* lds) {
    __builtin_amdgcn_global_load_lds(
        (const __attribute__((address_space(1))) void*)g,
        (__attribute__((address_space(3))) void*)lds, 16, 0, 0);
}

// ---------------------------------------------------------------------------
// int5 block-64 MSE quant-dequant -> bf16, both weights in one launch
// ---------------------------------------------------------------------------
__global__ __launch_bounds__(256) void quant2_bf16_kernel(
    const float* __restrict__ w0, __hip_bfloat16* __restrict__ o0,
    const float* __restrict__ w1, __hip_bfloat16* __restrict__ o1, int nEach)
{
#pragma clang fp contract(off)
    int b = blockIdx.x * 256 + threadIdx.x;
    const float* w; __hip_bfloat16* o; int bb;
    if (b < nEach) { w = w0; o = o0; bb = b; }
    else           { w = w1; o = o1; bb = b - nEach; }
    const float4* src = (const float4*)(w + (size_t)bb * 64);
    float v[64];
#pragma unroll
    for (int i = 0; i < 16; ++i) {
        float4 t = src[i];
        v[i*4+0] = t.x; v[i*4+1] = t.y; v[i*4+2] = t.z; v[i*4+3] = t.w;
    }
    float amax = 0.0f;
#pragma unroll
    for (int i = 0; i < 64; ++i) amax = fmaxf(amax, fabsf(v[i]));
    float base = fmaxf(amax, 1e-8f) / 15.0f;

    float best_err = __builtin_inff();
    float best_scale = base, best_rs = 0.0f;
    for (int k = 0; k < 16; ++k) {
        double sd = (k == 15) ? 1.0 : ((double)k * (0.6 / 15.0) + 0.4);
        float scale = base * (float)sd;
        float rs = 1.0f / scale;
        float err = 0.0f;
#pragma unroll
        for (int i = 0; i < 64; ++i) {
            float q = rintf(v[i] * rs);
            q = fminf(fmaxf(q, -15.0f), 15.0f);
            float d = q * scale - v[i];
            err = err + d * d;
        }
        if (err < best_err) { best_err = err; best_scale = scale; best_rs = rs; }
    }
    __hip_bfloat16* dst = o + (size_t)bb * 64;
#pragma unroll
    for (int i = 0; i < 64; ++i) {
        float q = rintf(v[i] * best_rs);
        q = fminf(fmaxf(q, -15.0f), 15.0f);
        dst[i] = __float2bfloat16(q * best_scale);
    }
}

__global__ __launch_bounds__(256) void f32_to_bf16_kernel(
    const float* __restrict__ in, __hip_bfloat16* __restrict__ out, int n8)
{
    int i = blockIdx.x * 256 + threadIdx.x;
    if (i >= n8) return;
    const float4* p = (const float4*)(in + (size_t)i * 8);
    float4 a = p[0], b = p[1];
    alignas(16) __hip_bfloat16 r[8];
    r[0] = __float2bfloat16(a.x); r[1] = __float2bfloat16(a.y);
    r[2] = __float2bfloat16(a.z); r[3] = __float2bfloat16(a.w);
    r[4] = __float2bfloat16(b.x); r[5] = __float2bfloat16(b.y);
    r[6] = __float2bfloat16(b.z); r[7] = __float2bfloat16(b.w);
    *(uint4*)(out + (size_t)i * 8) = *(const uint4*)r;
}

// ---------------------------------------------------------------------------
// m201-style 8-phase: 256x256, BK=64, 8 waves (2Mx4N), 16x16x32 MFMA.
// Phase = (A-quadrant mq, B-half nh). A-quad/B-halves held in regs across
// phases (ds_reads/phase: 12,4,8,0). Staging units land >=5 phases before
// first use; vmcnt(8) at every phase end drains only ~5-phase-old loads.
// Full WAR/RAW ledger in round notes. Prologue: T0 full + T1.{A,B}-q0,
// vmcnt(4). Tail iter: ph3 vmcnt(0).
// ---------------------------------------------------------------------------
#define SB0() __builtin_amdgcn_sched_barrier(0)
#define BARRIER() { SB0(); __builtin_amdgcn_s_barrier(); SB0(); }
#define LGKM0() { asm volatile("s_waitcnt lgkmcnt(0)" ::: "memory"); SB0(); }
#define LGKM8() { asm volatile("s_waitcnt lgkmcnt(8)" ::: "memory"); SB0(); }
#define VM8()   { asm volatile("s_waitcnt vmcnt(8)" ::: "memory"); SB0(); }
#define VM0()   { asm volatile("s_waitcnt vmcnt(0)" ::: "memory"); SB0(); }

#define RD_AQ(aq, bufOff, mq) { \
  _Pragma("unroll") for (int m_ = 0; m_ < 4; ++m_) { \
    aq[m_][0] = *(const bf16x8*)(smem + (bufOff) + (mq)*16384u + aRd + (uint)m_*2048u + koff0); \
    aq[m_][1] = *(const bf16x8*)(smem + (bufOff) + (mq)*16384u + aRd + (uint)m_*2048u + koff1); } }

#define RD_BH(bq, bufOff, nh) { \
  _Pragma("unroll") for (int n_ = 0; n_ < 2; ++n_) { \
    bq[n_][0] = *(const bf16x8*)(smem + (bufOff) + 32768u + (nh)*16384u + bRd + (uint)n_*2048u + koff0); \
    bq[n_][1] = *(const bf16x8*)(smem + (bufOff) + 32768u + (nh)*16384u + bRd + (uint)n_*2048u + koff1); } }

#define MFQ(mq, nh, aq, bq) { \
  _Pragma("unroll") for (int m_ = 0; m_ < 4; ++m_) \
  _Pragma("unroll") for (int n_ = 0; n_ < 2; ++n_) { \
    acc[(mq)*4+m_][(nh)*2+n_] = __builtin_amdgcn_mfma_f32_16x16x32_bf16( \
        aq[m_][0], bq[n_][0], acc[(mq)*4+m_][(nh)*2+n_],0,0,0); \
    acc[(mq)*4+m_][(nh)*2+n_] = __builtin_amdgcn_mfma_f32_16x16x32_bf16( \
        aq[m_][1], bq[n_][1], acc[(mq)*4+m_][(nh)*2+n_],0,0,0); } }

#define STAGE_A(bufbase, r, kk) \
    gload_lds16(uA + (size_t)(aG[r] + (kk)), smem + (bufbase) + (r)*8192u + wOff)
#define STAGE_B(bufbase, r, kk) \
    gload_lds16(uB + (size_t)(bG[r] + (kk)), smem + (bufbase) + 32768u + (r)*8192u + wOff)

template <int EPI>  // 0: C=bf16(relu(acc)^2), 1: C=f32 acc
__global__ __launch_bounds__(512) void gemm256_kernel(
    const __hip_bfloat16* __restrict__ A,   // M x K
    const __hip_bfloat16* __restrict__ B,   // N x K
    void* __restrict__ Cout, int M, int N, int K)
{
    extern __shared__ char smem[];

    const int t    = threadIdx.x;
    const int lane = t & 63;
    const int w    = t >> 6;
    const int wr   = w >> 2;        // 0..1
    const int wc   = w & 3;         // 0..3
    const int lo   = lane & 15;
    const int hi   = lane >> 4;
    const uint wOff = (uint)w * 1024u;

    const int cpx = gridDim.x >> 3;
    int bid = blockIdx.x;
    bid = (bid & 7) * cpx + (bid >> 3);
    const int nN = N >> 8;
    const int bm = bid / nN;
    const int bn = bid % nN;
    const int rowBase = bm << 8;
    const int colBase = bn << 8;

    const __hip_bfloat16* uA = A + (size_t)rowBase * (size_t)K;
    const __hip_bfloat16* uB = B + (size_t)colBase * (size_t)K;

    // staging source offsets (inverse-swizzled, region-local)
    uint o = wOff + (uint)lane * 16u;
    uint p = o ^ (((o >> 7) & 7u) << 4);
    const uint lrow = p >> 7;                  // 0..63
    const uint elem = (p & 127u) >> 1;
    uint aG[4], bG[4];
    aG[0] = (0u   + lrow) * (uint)K + elem;
    aG[1] = (128u + lrow) * (uint)K + elem;
    aG[2] = (64u  + lrow) * (uint)K + elem;
    aG[3] = (192u + lrow) * (uint)K + elem;
    const uint bb = (lrow >> 5) * 64u + (lrow & 31u);
    bG[0] = (bb +   0u) * (uint)K + elem;
    bG[1] = (bb + 128u) * (uint)K + elem;
    bG[2] = (bb +  32u) * (uint)K + elem;
    bG[3] = (bb + 160u) * (uint)K + elem;

    // fragment read addressing (swizzled; conflict-free, r4 class)
    const uint sw    = (uint)(lo & 7) << 4;
    const uint aRd   = (uint)wr * 8192u + (uint)lo * 128u;
    const uint bRd   = (uint)wc * 4096u + (uint)lo * 128u;
    const uint koff0 = ((uint)hi * 16u)        ^ sw;
    const uint koff1 = (64u + (uint)hi * 16u)  ^ sw;

    f32x4 acc[8][4] = {};
    bf16x8 aq[4][2], bq0[2][2], bq1[2][2];

    // ---- prologue: T0 full -> buf0; T1.A-q0,B-q0 -> buf1 ----
    STAGE_A(0u, 0, 0u); STAGE_A(0u, 1, 0u); STAGE_A(0u, 2, 0u); STAGE_A(0u, 3, 0u);
    STAGE_B(0u, 0, 0u); STAGE_B(0u, 1, 0u); STAGE_B(0u, 2, 0u); STAGE_B(0u, 3, 0u);
    STAGE_A(65536u, 0, 64u); STAGE_A(65536u, 1, 64u);
    STAGE_B(65536u, 0, 64u); STAGE_B(65536u, 1, 64u);
    asm volatile("s_waitcnt vmcnt(4)" ::: "memory");
    BARRIER();

    const int NI = K >> 7;
    for (int P = 0; P < NI; ++P) {
        const bool pf = (P + 1 < NI);
        const uint kT1 = ((uint)(2 * P + 1)) << 6;
        const uint kT2 = kT1 + 64u;
        const uint kT3 = kT1 + 128u;

        // ph0
        RD_AQ(aq, 0u, 0); RD_BH(bq0, 0u, 0);
        STAGE_B(65536u, 2, kT1); STAGE_B(65536u, 3, kT1);
        LGKM8();
        BARRIER(); LGKM0();
        __builtin_amdgcn_s_setprio(1); MFQ(0, 0, aq, bq0); __builtin_amdgcn_s_setprio(0);
        VM8(); BARRIER();

        // ph1
        RD_BH(bq1, 0u, 1);
        STAGE_A(65536u, 2, kT1); STAGE_A(65536u, 3, kT1);
        BARRIER(); LGKM0();
        __builtin_amdgcn_s_setprio(1); MFQ(0, 1, aq, bq1); __builtin_amdgcn_s_setprio(0);
        VM8(); BARRIER();

        // ph2
        RD_AQ(aq, 0u, 1);
        if (pf) { STAGE_A(0u, 0, kT2); STAGE_A(0u, 1, kT2); }
        BARRIER(); LGKM0();
        __builtin_amdgcn_s_setprio(1); MFQ(1, 0, aq, bq0); __builtin_amdgcn_s_setprio(0);
        VM8(); BARRIER();

        // ph3
        if (pf) { STAGE_B(0u, 0, kT2); STAGE_B(0u, 1, kT2); }
        BARRIER();
        __builtin_amdgcn_s_setprio(1); MFQ(1, 1, aq, bq1); __builtin_amdgcn_s_setprio(0);
        if (pf) { VM8(); } else { VM0(); }
        BARRIER();

        // ph4
        RD_AQ(aq, 65536u, 0); RD_BH(bq0, 65536u, 0);
        if (pf) { STAGE_B(0u, 2, kT2); STAGE_B(0u, 3, kT2); }
        LGKM8();
        BARRIER(); LGKM0();
        __builtin_amdgcn_s_setprio(1); MFQ(0, 0, aq, bq0); __builtin_amdgcn_s_setprio(0);
        VM8(); BARRIER();

        // ph5
        RD_BH(bq1, 65536u, 1);
        if (pf) { STAGE_A(0u, 2, kT2); STAGE_A(0u, 3, kT2); }
        BARRIER(); LGKM0();
        __builtin_amdgcn_s_setprio(1); MFQ(0, 1, aq, bq1); __builtin_amdgcn_s_setprio(0);
        VM8(); BARRIER();

        // ph6
        RD_AQ(aq, 65536u, 1);
        if (pf) { STAGE_A(65536u, 0, kT3); STAGE_A(65536u, 1, kT3); }
        BARRIER(); LGKM0();
        __builtin_amdgcn_s_setprio(1); MFQ(1, 0, aq, bq0); __builtin_amdgcn_s_setprio(0);
        VM8(); BARRIER();

        // ph7
        if (pf) { STAGE_B(65536u, 0, kT3); STAGE_B(65536u, 1, kT3); }
        BARRIER();
        __builtin_amdgcn_s_setprio(1); MFQ(1, 1, aq, bq1); __builtin_amdgcn_s_setprio(0);
        VM8(); BARRIER();
    }

    // ---- epilogue: quadrant mapping; 16x16 C/D: col=lo, row=hi*4+rr ----
    if (EPI == 0) {
        __hip_bfloat16* Cb = (__hip_bfloat16*)Cout;
#pragma unroll
        for (int i = 0; i < 8; ++i)
#pragma unroll
            for (int j = 0; j < 4; ++j)
#pragma unroll
                for (int rr = 0; rr < 4; ++rr) {
                    size_t row = rowBase + wr*128 + (i>>2)*64 + (i&3)*16 + hi*4 + rr;
                    size_t col = colBase + wc*64 + (j>>1)*32 + (j&1)*16 + lo;
                    float v = fmaxf(acc[i][j][rr], 0.0f);
                    Cb[row * N + col] = __float2bfloat16(v * v);
                }
    } else {
        float* Cf = (float*)Cout;
#pragma unroll
        for (int i = 0; i < 8; ++i)
#pragma unroll
            for (int j = 0; j < 4; ++j)
#pragma unroll
                for (int rr = 0; rr < 4; ++rr) {
                    size_t row = rowBase + wr*128 + (i>>2)*64 + (i&3)*16 + hi*4 + rr;
                    size_t col = colBase + wc*64 + (j>>1)*32 + (j&1)*16 + lo;
                    Cf[row * N + col] = acc[i][j][rr];
                }
    }
}

// ---------------------------------------------------------------------------
extern "C" void kernel_launch(void* const* d_in, const int* in_sizes, int n_in,
                              void* d_out, int out_size, void* d_ws, size_t ws_size,
                              hipStream_t stream) {
    const float* x      = (const float*)d_in[0];  // 8192 x 2048
    const float* w_fc   = (const float*)d_in[1];  // 8192 x 2048
    const float* w_proj = (const float*)d_in[2];  // 2048 x 8192
    float* out = (float*)d_out;                   // 8192 x 2048

    const int DIM = 2048, HID = 8192, M = 8192;

    char* ws = (char*)d_ws;
    __hip_bfloat16* Xb  = (__hip_bfloat16*)ws;
    __hip_bfloat16* Wfc = (__hip_bfloat16*)(ws + (size_t)M * DIM * 2);
    __hip_bfloat16* Wpj = (__hip_bfloat16*)(ws + (size_t)(M * DIM + (size_t)HID * DIM) * 2);
    __hip_bfloat16* H2  = (__hip_bfloat16*)(ws + (size_t)(M * DIM + 2 * (size_t)HID * DIM) * 2);

    (void)hipFuncSetAttribute((const void*)gemm256_kernel<0>,
                              hipFuncAttributeMaxDynamicSharedMemorySize, 131072);
    (void)hipFuncSetAttribute((const void*)gemm256_kernel<1>,
                              hipFuncAttributeMaxDynamicSharedMemorySize, 131072);

    int nblk = HID * DIM / 64;   // 262144 per weight
    quant2_bf16_kernel<<<2 * nblk / 256, 256, 0, stream>>>(
        w_fc, Wfc, w_proj, Wpj, nblk);

    int n8 = M * DIM / 8;
    f32_to_bf16_kernel<<<n8 / 256, 256, 0, stream>>>(x, Xb, n8);

    // H2 = bf16( relu(X @ Wfc^T)^2 )  [8192 x 8192]
    gemm256_kernel<0><<<(M/256)*(HID/256), 512, 131072, stream>>>(
        Xb, Wfc, (void*)H2, M, HID, DIM);

    // out = H2 @ Wpj^T  [8192 x 2048] f32
    gemm256_kernel<1><<<(M/256)*(DIM/256), 512, 131072, stream>>>(
        H2, Wpj, (void*)out, M, DIM, HID);
}